// Round 5
// baseline (412.055 us; speedup 1.0000x reference)
//
#include <hip/hip_runtime.h>
#include <math.h>

// Problem constants
#define B_SZ 256
#define N_SZ 100000
#define E_SZ 1280
#define D_SZ 512

#define NCH 1563   // ceil(100000 / 64) j-chunks

typedef __attribute__((ext_vector_type(8))) short s8v;   // 8 bf16
typedef __attribute__((ext_vector_type(4))) float f32x4; // MFMA acc

__device__ __forceinline__ unsigned short f2bf(float f) {
  unsigned int u = __float_as_uint(f);
  u += 0x7fffu + ((u >> 16) & 1u);   // RNE
  return (unsigned short)(u >> 16);
}
__device__ __forceinline__ unsigned int pack2(float a, float b) {
  return (unsigned)f2bf(a) | ((unsigned)f2bf(b) << 16);
}

// async global->LDS, 16B per lane; LDS dest = wave-uniform base + lane*16
__device__ __forceinline__ void gload16(const void* g, void* l) {
  __builtin_amdgcn_global_load_lds(
      (const __attribute__((address_space(1))) void*)g,
      (__attribute__((address_space(3))) void*)l, 16, 0, 0);
}

// top-8 streaming update; requires locals: bv[8], bi[8], minv, mins
#define TOP8_UPDATE(v_, i_)                                                 \
  if ((v_) > minv) {                                                        \
    _Pragma("unroll")                                                       \
    for (int s_ = 0; s_ < 8; ++s_)                                          \
      if (s_ == mins) { bv[s_] = (v_); bi[s_] = (i_); }                     \
    minv = bv[0]; mins = 0;                                                 \
    _Pragma("unroll")                                                       \
    for (int s_ = 1; s_ < 8; ++s_)                                          \
      if (bv[s_] < minv) { minv = bv[s_]; mins = s_; }                      \
  }

// ---------------- kernel 1: L2-normalize queries -> bf16 ----------------
__global__ __launch_bounds__(256) void k_normq(const float* __restrict__ q,
                                               unsigned short* __restrict__ qn) {
  __shared__ float red[4];
  int row = blockIdx.x, t = threadIdx.x;
  const float* src = q + (size_t)row * E_SZ;
  float x[5];
  float ss = 0.f;
#pragma unroll
  for (int i = 0; i < 5; ++i) { x[i] = src[t + 256 * i]; ss += x[i] * x[i]; }
#pragma unroll
  for (int o = 32; o > 0; o >>= 1) ss += __shfl_down(ss, o, 64);
  if ((t & 63) == 0) red[t >> 6] = ss;
  __syncthreads();
  float nrm = sqrtf(red[0] + red[1] + red[2] + red[3]);
  nrm = fmaxf(nrm, 1e-12f);
  float inv = 1.0f / nrm;
  unsigned short* dst = qn + (size_t)row * E_SZ;
#pragma unroll
  for (int i = 0; i < 5; ++i) dst[t + 256 * i] = f2bf(x[i] * inv);
}

// ---------------- kernel 1b: transpose+convert projW -> Wt bf16 [512][1280] --
__global__ __launch_bounds__(256) void k_wt(const float* __restrict__ W,
                                            unsigned short* __restrict__ Wt) {
  __shared__ float T[64][65];
  const int kb = blockIdx.x * 64;   // 20 k-tiles
  const int nb = blockIdx.y * 64;   // 8 n-tiles
  const int t = threadIdx.x;
#pragma unroll
  for (int i = 0; i < 16; ++i) {
    int kr = i * 4 + (t >> 6);
    T[kr][t & 63] = W[(size_t)(kb + kr) * D_SZ + nb + (t & 63)];
  }
  __syncthreads();
  const int n = t >> 2, ks = (t & 3) * 16;
  unsigned int ow[8];
#pragma unroll
  for (int j = 0; j < 8; ++j)
    ow[j] = (unsigned)f2bf(T[ks + 2 * j][n]) |
            ((unsigned)f2bf(T[ks + 2 * j + 1][n]) << 16);
  unsigned short* dst = Wt + (size_t)(nb + n) * E_SZ + kb + ks;
  *(uint4*)dst = make_uint4(ow[0], ow[1], ow[2], ow[3]);
  *(uint4*)(dst + 8) = make_uint4(ow[4], ow[5], ow[6], ow[7]);
}

// ---------------- kernel 2: bf16 MFMA sims + fused per-chunk top-8 ----------
// 1563 blocks x 256 thr (4 waves). Tile 256q x 64j, K=1280 in 40 steps of 32.
// A (qn bf16) staged via global_load_lds (source-swizzled, LDS linear).
// B (emb f32) reg-staged 2-deep, converted, swizzled linear ds_write_b128.
// Fence = counted s_waitcnt vmcnt(2) + raw barrier (loads cross barriers).
__global__ __launch_bounds__(256) void k_sims_topk(
    const unsigned short* __restrict__ qn, const float* __restrict__ emb,
    const int* __restrict__ excl, float* __restrict__ cval) {
  __shared__ __align__(16) char lds[40960];
  // A0 @0 (16K), A1 @16384, B0 @32768 (4K), B1 @36864
  const int t = threadIdx.x;
  const int l = t & 63, w = t >> 6;
  const int r15 = l & 15, g = l >> 4;
  const int jbase = blockIdx.x * 64;
  const int myq = (w << 6) + l;
  const int ex = excl[myq];

  f32x4 acc[4][4];
#pragma unroll
  for (int i = 0; i < 4; ++i)
#pragma unroll
    for (int j = 0; j < 4; ++j) acc[i][j] = (f32x4)0.f;

  // staging thread mapping: row = t>>2 (+64*i for A issues), pos p = t&3,
  // source chunk c = p ^ ((row>>1)&3) = (t&3) ^ ((t>>3)&3)
  const int chunk = (t & 3) ^ ((t >> 3) & 3);
  const unsigned short* aSrc0 = qn + (size_t)(t >> 2) * E_SZ + chunk * 8;
  const int grow = min(jbase + (t >> 2), N_SZ - 1);
  const float* bSrc = emb + (size_t)grow * E_SZ + chunk * 8;
  const int bwr = t * 16;   // linear B dest byte offset

  // fragment read offsets: stored chunk at pos p is p ^ ((row>>1)&3);
  // for rows = base16 + r15 this reduces to g ^ ((r15>>1)&3)
  const int fsw = ((g ^ ((r15 >> 1) & 3)) << 4);
  int afoff[4], bfoff[4];
#pragma unroll
  for (int mq = 0; mq < 4; ++mq)
    afoff[mq] = ((w << 6) + mq * 16 + r15) * 64 + fsw;
#pragma unroll
  for (int nj = 0; nj < 4; ++nj)
    bfoff[nj] = (nj * 16 + r15) * 64 + fsw;

  float4 bw0[2], bw1[2];

#define STAGEA(kt_, aoff_)                                                   \
  { _Pragma("unroll") for (int i_ = 0; i_ < 4; ++i_)                         \
      gload16(aSrc0 + (size_t)i_ * (64 * E_SZ) + (kt_),                      \
              lds + (aoff_) + i_ * 4096 + w * 1024); }
#define LOADB(br_, kt_)                                                      \
  { br_[0] = *(const float4*)(bSrc + (kt_));                                 \
    br_[1] = *(const float4*)(bSrc + (kt_) + 4); }
#define CVTWR(br_, boff_)                                                    \
  { uint4 p_;                                                                \
    p_.x = pack2(br_[0].x, br_[0].y); p_.y = pack2(br_[0].z, br_[0].w);      \
    p_.z = pack2(br_[1].x, br_[1].y); p_.w = pack2(br_[1].z, br_[1].w);      \
    *(uint4*)(lds + (boff_) + bwr) = p_; }
#define COMPUTE(aoff_, boff_)                                                \
  { s8v af_[4];                                                              \
    _Pragma("unroll") for (int mq_ = 0; mq_ < 4; ++mq_)                      \
      af_[mq_] = *(const s8v*)(lds + (aoff_) + afoff[mq_]);                  \
    _Pragma("unroll") for (int nj_ = 0; nj_ < 4; ++nj_) {                    \
      s8v bf_ = *(const s8v*)(lds + (boff_) + bfoff[nj_]);                   \
      _Pragma("unroll") for (int mq_ = 0; mq_ < 4; ++mq_)                    \
        acc[mq_][nj_] = __builtin_amdgcn_mfma_f32_16x16x32_bf16(             \
            af_[mq_], bf_, acc[mq_][nj_], 0, 0, 0);                          \
    } }
#define FENCE2                                                               \
  { asm volatile("s_waitcnt vmcnt(2) lgkmcnt(0)" ::: "memory");              \
    __builtin_amdgcn_s_barrier(); }
#define FENCE0                                                               \
  { asm volatile("s_waitcnt vmcnt(0) lgkmcnt(0)" ::: "memory");              \
    __builtin_amdgcn_s_barrier(); }

  // prologue: tile0 -> Abuf0/Bbuf0; tile1 B regs in flight
  STAGEA(0, 0);
  LOADB(bw0, 0);
  LOADB(bw1, 32);
  CVTWR(bw0, 32768);
  FENCE2;

  for (int s = 0; s < 40; s += 2) {
    // even step s: compute buf0; stage A(s+1)->Abuf1; B(s+2)->bw0; write bw1->Bbuf1
    STAGEA((s + 1) * 32, 16384);
    if (s + 2 < 40) LOADB(bw0, (s + 2) * 32);
    COMPUTE(0, 32768);
    CVTWR(bw1, 36864);
    if (s + 2 < 40) { FENCE2; } else { FENCE0; }
    // odd step s+1: compute buf1; stage A(s+2)->Abuf0; B(s+3)->bw1; write bw0->Bbuf0
    if (s + 2 < 40) STAGEA((s + 2) * 32, 0);
    if (s + 3 < 40) LOADB(bw1, (s + 3) * 32);
    COMPUTE(16384, 36864);
    if (s + 2 < 40) CVTWR(bw0, 32768);
    if (s + 3 < 40) { FENCE2; } else { FENCE0; }
  }

  // ---- wave-local top-8 scan, 2 phases (waves {0,1} then {2,3}) ----
  for (int ph = 0; ph < 2; ++ph) {
    if ((w >> 1) == ph) {
      float* Sbuf = (float*)(lds + (w & 1) * 16640);  // 64 x 65 f32
#pragma unroll
      for (int mq = 0; mq < 4; ++mq)
#pragma unroll
        for (int nj = 0; nj < 4; ++nj)
#pragma unroll
          for (int r = 0; r < 4; ++r)
            Sbuf[(16 * mq + 4 * g + r) * 65 + 16 * nj + r15] = acc[mq][nj][r];
      float bv[8]; int bi[8];
#pragma unroll
      for (int s = 0; s < 8; ++s) { bv[s] = -1e30f; bi[s] = 0; }
      float minv = -1e30f; int mins = 0;
      const float* Srow = Sbuf + l * 65;
      for (int c = 0; c < 64; ++c) {
        int gj = jbase + c;
        float v = Srow[c];
        if (gj < N_SZ && gj != ex) { TOP8_UPDATE(v, gj); }
      }
      float* vdst = cval + (size_t)blockIdx.x * 4096 + myq * 8;
      *(float4*)vdst = make_float4(bv[0], bv[1], bv[2], bv[3]);
      *(float4*)(vdst + 4) = make_float4(bv[4], bv[5], bv[6], bv[7]);
      int* idst = (int*)(cval + (size_t)blockIdx.x * 4096 + 2048) + myq * 8;
      *(int4*)idst = make_int4(bi[0], bi[1], bi[2], bi[3]);
      *(int4*)(idst + 4) = make_int4(bi[4], bi[5], bi[6], bi[7]);
    }
    __syncthreads();
  }
#undef STAGEA
#undef LOADB
#undef CVTWR
#undef COMPUTE
#undef FENCE2
#undef FENCE0
}

// ---------------- kernel 3: merge per-chunk candidates -> global top-8 ------
__global__ __launch_bounds__(256) void k_merge(const float* __restrict__ cval,
                                               int* __restrict__ topk) {
  __shared__ float sv[2048];
  __shared__ int si[2048];
  const int q = blockIdx.x, t = threadIdx.x;
  float bv[8]; int bi[8];
#pragma unroll
  for (int s = 0; s < 8; ++s) { bv[s] = -1e30f; bi[s] = 0; }
  float minv = -1e30f; int mins = 0;
  for (int c = t; c < NCH; c += 256) {
    const float* vp = cval + (size_t)c * 4096 + q * 8;
    const int* ip = (const int*)(cval + (size_t)c * 4096 + 2048) + q * 8;
    float4 v0 = *(const float4*)vp, v1 = *(const float4*)(vp + 4);
    int4 i0 = *(const int4*)ip, i1 = *(const int4*)(ip + 4);
    float va[8] = {v0.x, v0.y, v0.z, v0.w, v1.x, v1.y, v1.z, v1.w};
    int ia[8] = {i0.x, i0.y, i0.z, i0.w, i1.x, i1.y, i1.z, i1.w};
#pragma unroll
    for (int s = 0; s < 8; ++s) {
      float v = va[s]; int ix = ia[s];
      TOP8_UPDATE(v, ix);
    }
  }
#pragma unroll
  for (int s = 0; s < 8; ++s) { sv[t * 8 + s] = bv[s]; si[t * 8 + s] = bi[s]; }
  __syncthreads();
  if (t < 64) {
    for (int rr = 1; rr < 4; ++rr) {
      int r = t + rr * 64;
#pragma unroll
      for (int s = 0; s < 8; ++s) {
        float v = sv[r * 8 + s]; int ix = si[r * 8 + s];
        TOP8_UPDATE(v, ix);
      }
    }
#pragma unroll
    for (int s = 0; s < 8; ++s) { sv[t * 8 + s] = bv[s]; si[t * 8 + s] = bi[s]; }
  }
  __syncthreads();
  if (t < 8) {
    for (int rr = 1; rr < 8; ++rr) {
      int r = t + rr * 8;
#pragma unroll
      for (int s = 0; s < 8; ++s) {
        float v = sv[r * 8 + s]; int ix = si[r * 8 + s];
        TOP8_UPDATE(v, ix);
      }
    }
#pragma unroll
    for (int s = 0; s < 8; ++s) { sv[t * 8 + s] = bv[s]; si[t * 8 + s] = bi[s]; }
  }
  __syncthreads();
  if (t == 0) {
    for (int r = 1; r < 8; ++r) {
#pragma unroll
      for (int s = 0; s < 8; ++s) {
        float v = sv[r * 8 + s]; int ix = si[r * 8 + s];
        TOP8_UPDATE(v, ix);
      }
    }
#pragma unroll
    for (int s = 0; s < 8; ++s) topk[q * 8 + s] = bi[s];
  }
}

// ---------------- kernel 4: gather + project via MFMA, bias fused -----------
// grid (16 Mtiles, 4 Ntiles), 256 thr (2x2 waves), tile 128x128, K=1280/64.
__global__ __launch_bounds__(256) void k_proj(
    const float* __restrict__ emb, const int* __restrict__ topk,
    const unsigned short* __restrict__ Wt, const float* __restrict__ bias,
    float* __restrict__ nproj) {
  __shared__ __align__(16) char lds[65536];  // A0 A1 B0 B1 each 16K
  const int t = threadIdx.x, l = t & 63, w = t >> 6;
  const int r15 = l & 15, g = l >> 4;
  const int wm = w >> 1, wn = w & 1;
  const int r0 = blockIdx.x * 128, n0 = blockIdx.y * 128;
  const int sr = t >> 3, kc = t & 7;

  int grow[4];
#pragma unroll
  for (int i = 0; i < 4; ++i) grow[i] = topk[r0 + i * 32 + sr];

  int woff[4];
#pragma unroll
  for (int i = 0; i < 4; ++i) {
    int row = i * 32 + sr;
    woff[i] = row * 128 + (((kc + (row & 7)) & 7) << 4);
  }
  int afoff[2][4], bfoff[2][4];
#pragma unroll
  for (int h = 0; h < 2; ++h) {
#pragma unroll
    for (int qq = 0; qq < 4; ++qq) {
      int rowa = 64 * wm + 16 * qq + r15;
      afoff[h][qq] = rowa * 128 + ((((h << 2) + g + (rowa & 7)) & 7) << 4);
      int rowb = 64 * wn + 16 * qq + r15;
      bfoff[h][qq] = rowb * 128 + ((((h << 2) + g + (rowb & 7)) & 7) << 4);
    }
  }

  f32x4 acc[4][4];
#pragma unroll
  for (int i = 0; i < 4; ++i)
#pragma unroll
    for (int j = 0; j < 4; ++j) acc[i][j] = (f32x4)0.f;

  float4 aset[4][2];
  s8v bset[4];

#define PLOADA(kt_)                                                          \
  { _Pragma("unroll") for (int i_ = 0; i_ < 4; ++i_) {                       \
      const float* s_ = emb + (size_t)grow[i_] * E_SZ + (kt_) + kc * 8;      \
      aset[i_][0] = *(const float4*)s_;                                      \
      aset[i_][1] = *(const float4*)(s_ + 4); } }
#define PLOADB(kt_)                                                          \
  { _Pragma("unroll") for (int i_ = 0; i_ < 4; ++i_)                         \
      bset[i_] = *(const s8v*)(Wt + (size_t)(n0 + i_ * 32 + sr) * E_SZ +     \
                               (kt_) + kc * 8); }
#define PWR(bA_, bB_)                                                        \
  { _Pragma("unroll") for (int i_ = 0; i_ < 4; ++i_) {                       \
      uint4 p_;                                                              \
      p_.x = pack2(aset[i_][0].x, aset[i_][0].y);                            \
      p_.y = pack2(aset[i_][0].z, aset[i_][0].w);                            \
      p_.z = pack2(aset[i_][1].x, aset[i_][1].y);                            \
      p_.w = pack2(aset[i_][1].z, aset[i_][1].w);                            \
      *(uint4*)((bA_) + woff[i_]) = p_;                                      \
      *(s8v*)((bB_) + woff[i_]) = bset[i_]; } }
#define PCOMP(bA_, bB_)                                                      \
  { _Pragma("unroll") for (int h_ = 0; h_ < 2; ++h_) {                       \
      s8v af_[4], bf_[4];                                                    \
      _Pragma("unroll") for (int q_ = 0; q_ < 4; ++q_) {                     \
        af_[q_] = *(const s8v*)((bA_) + afoff[h_][q_]);                      \
        bf_[q_] = *(const s8v*)((bB_) + bfoff[h_][q_]); }                    \
      _Pragma("unroll") for (int nj_ = 0; nj_ < 4; ++nj_)                    \
        _Pragma("unroll") for (int mq_ = 0; mq_ < 4; ++mq_)                  \
          acc[mq_][nj_] = __builtin_amdgcn_mfma_f32_16x16x32_bf16(           \
              af_[mq_], bf_[nj_], acc[mq_][nj_], 0, 0, 0); } }

  PLOADA(0); PLOADB(0);
  PWR(lds, lds + 32768);
  __syncthreads();
  for (int s = 0; s < 20; ++s) {
    char* cA = lds + (s & 1) * 16384;
    char* cB = lds + 32768 + (s & 1) * 16384;
    char* nA = lds + ((s + 1) & 1) * 16384;
    char* nB = lds + 32768 + ((s + 1) & 1) * 16384;
    if (s + 1 < 20) { PLOADA((s + 1) * 64); PLOADB((s + 1) * 64); }
    PCOMP(cA, cB);
    if (s + 1 < 20) { PWR(nA, nB); }
    __syncthreads();
  }
#pragma unroll
  for (int nj = 0; nj < 4; ++nj) {
    int n = n0 + 64 * wn + 16 * nj + r15;
    float bn = bias[n];
#pragma unroll
    for (int mq = 0; mq < 4; ++mq) {
      int m = r0 + 64 * wm + 16 * mq + 4 * g;
#pragma unroll
      for (int r = 0; r < 4; ++r)
        nproj[(size_t)(m + r) * D_SZ + n] = acc[mq][nj][r] + bn;
    }
  }
#undef PLOADA
#undef PLOADB
#undef PWR
#undef PCOMP
}

// ---------------- kernel 5: attention + logits + per-query loss partial -----
__global__ __launch_bounds__(256) void k_attn(
    const float* __restrict__ model, const float* __restrict__ proj,
    const int* __restrict__ topk, const int* __restrict__ labels,
    const float* __restrict__ clfW, const float* __restrict__ clfb,
    float* __restrict__ out, float* __restrict__ lossp) {
  __shared__ float P[8 * 512];
  __shared__ float red[4];
  int b = blockIdx.x, t = threadIdx.x;
  const float* src = proj + (size_t)b * 8 * 512;
#pragma unroll
  for (int i = 0; i < 4; ++i) {
    int o = i * 1024 + t * 4;
    *(float4*)&P[o] = *(const float4*)&src[o];
  }
  __syncthreads();
  float m0 = model[b * 512 + t], m1 = model[b * 512 + 256 + t];

  float sc[8];
#pragma unroll
  for (int k = 0; k < 8; ++k) {
    float p = m0 * P[k * 512 + t] + m1 * P[k * 512 + 256 + t];
#pragma unroll
    for (int o = 32; o > 0; o >>= 1) p += __shfl_down(p, o, 64);
    if ((t & 63) == 0) red[t >> 6] = p;
    __syncthreads();
    sc[k] = red[0] + red[1] + red[2] + red[3];
    __syncthreads();
  }
  const float scale = 0.04419417382415922f;  // 1/sqrt(512)
  float mx = -1e30f;
  float s_[8];
#pragma unroll
  for (int k = 0; k < 8; ++k) { s_[k] = sc[k] * scale; mx = fmaxf(mx, s_[k]); }
  float den = 0.f, att[8];
#pragma unroll
  for (int k = 0; k < 8; ++k) { att[k] = expf(s_[k] - mx); den += att[k]; }
  float iden = 1.0f / den;
#pragma unroll
  for (int k = 0; k < 8; ++k) att[k] *= iden;

  float z0 = 0.f, z1 = 0.f;
#pragma unroll
  for (int k = 0; k < 8; ++k) {
    z0 = fmaf(att[k], P[k * 512 + t], z0);
    z1 = fmaf(att[k], P[k * 512 + 256 + t], z1);
  }
#pragma unroll
  for (int c = 0; c < 2; ++c) {
    float lp = m0 * clfW[t * 2 + c] + m1 * clfW[(t + 256) * 2 + c] +
               z0 * clfW[(512 + t) * 2 + c] + z1 * clfW[(768 + t) * 2 + c];
#pragma unroll
    for (int o = 32; o > 0; o >>= 1) lp += __shfl_down(lp, o, 64);
    if ((t & 63) == 0) red[t >> 6] = lp;
    __syncthreads();
    if (t == 0) out[b * 2 + c] = red[0] + red[1] + red[2] + red[3] + clfb[c];
    __syncthreads();
  }
  float cp = 0.f, cn = 0.f;
  float p0 = 0.f, p1 = 0.f, n0 = 0.f, n1 = 0.f;
#pragma unroll
  for (int k = 0; k < 8; ++k) {
    int lb = labels[topk[b * 8 + k]];
    float mp = (lb == 1) ? 1.f : 0.f;
    float mn = (lb == 0) ? 1.f : 0.f;
    cp += mp; cn += mn;
    p0 = fmaf(mp, P[k * 512 + t], p0);
    p1 = fmaf(mp, P[k * 512 + 256 + t], p1);
    n0 = fmaf(mn, P[k * 512 + t], n0);
    n1 = fmaf(mn, P[k * 512 + 256 + t], n1);
  }
  float icp = 1.0f / (cp + 1e-6f), icn = 1.0f / (cn + 1e-6f);
  p0 *= icp; p1 *= icp; n0 *= icn; n1 *= icn;
  float lq = (m0 - p0) * (m0 - p0) + (m1 - p1) * (m1 - p1) -
             0.5f * ((m0 - n0) * (m0 - n0) + (m1 - n1) * (m1 - n1));
#pragma unroll
  for (int o = 32; o > 0; o >>= 1) lq += __shfl_down(lq, o, 64);
  if ((t & 63) == 0) red[t >> 6] = lq;
  __syncthreads();
  if (t == 0) lossp[b] = red[0] + red[1] + red[2] + red[3];
}

// ---------------- kernel 6: final loss reduction ----------------
__global__ __launch_bounds__(256) void k_loss(const float* __restrict__ lossp,
                                              float* __restrict__ out) {
  __shared__ float red[4];
  int t = threadIdx.x;
  float v = lossp[t];
#pragma unroll
  for (int o = 32; o > 0; o >>= 1) v += __shfl_down(v, o, 64);
  if ((t & 63) == 0) red[t >> 6] = v;
  __syncthreads();
  if (t == 0)
    out[512] = (red[0] + red[1] + red[2] + red[3]) * (1.0f / (256.0f * 512.0f));
}

extern "C" void kernel_launch(void* const* d_in, const int* in_sizes, int n_in,
                              void* d_out, int out_size, void* d_ws,
                              size_t ws_size, hipStream_t stream) {
  (void)in_sizes; (void)n_in; (void)out_size; (void)ws_size;
  const float* q      = (const float*)d_in[0];  // [256,1280]
  const float* model  = (const float*)d_in[1];  // [256,512]
  const float* emb    = (const float*)d_in[2];  // [100000,1280]
  const int*   labels = (const int*)d_in[3];    // [100000]
  const int*   excl   = (const int*)d_in[4];    // [256]
  const float* projW  = (const float*)d_in[5];  // [1280,512]
  const float* projb  = (const float*)d_in[6];  // [512]
  const float* clfW   = (const float*)d_in[7];  // [1024,2]
  const float* clfb   = (const float*)d_in[8];  // [2]
  float* out = (float*)d_out;                   // 512 logits + 1 loss

  // workspace layout (bytes)
  char* ws = (char*)d_ws;
  unsigned short* qn = (unsigned short*)ws;               // 655,360
  unsigned short* Wt = (unsigned short*)(ws + 655360);    // 1,310,720
  float* cval  = (float*)(ws + 1966080);                  // 1563*4096*4 = 25,608,192
  int*   topk  = (int*)(ws + 27574272);                   // 8,192
  float* nproj = (float*)(ws + 27582464);                 // 4,194,304
  float* lossp = (float*)(ws + 31776768);                 // 1,024

  k_normq<<<256, 256, 0, stream>>>(q, qn);
  k_wt<<<dim3(20, 8), 256, 0, stream>>>(projW, Wt);
  k_sims_topk<<<NCH, 256, 0, stream>>>(qn, emb, excl, cval);
  k_merge<<<256, 256, 0, stream>>>(cval, topk);
  k_proj<<<dim3(16, 4), 256, 0, stream>>>(emb, topk, Wt, projb, nproj);
  k_attn<<<256, 256, 0, stream>>>(model, nproj, topk, labels, clfW, clfb, out, lossp);
  k_loss<<<1, 256, 0, stream>>>(lossp, out);
}